// Round 3
// baseline (1468.088 us; speedup 1.0000x reference)
//
#include <hip/hip_runtime.h>
#include <math.h>

// EM routing (DigitCaps) for B=16, N=16384, C=10, D=16, ITER_ROUTING=3.
// Strategy: one full pass over votes per routing iteration, accumulating
// unnormalized moments sum(r), sum(r*v), sum(r*v^2) per (b,c,d); tiny
// finalize kernels compute miu/sigma/act between passes. sigma via
// moment identity avoids an extra votes pass. Final act_out (beta_v/beta_a)
// is dead code w.r.t. the returned miu -> skipped.

namespace {
constexpr int BB = 16;
constexpr int NN = 16384;
constexpr int CC = 10;
constexpr int DD = 16;
constexpr float EPSF = 1e-9f;
constexpr int CHUNKS = 128;                    // blocks per batch b
constexpr int ROWS_PER_CHUNK = NN / CHUNKS;    // 128 rows per block
// workspace (float) layout
constexpr int ACC_SZ = BB * CC * DD * 2 + BB * CC;  // rv | rv2 | rsum = 5280
constexpr int RV_OFF = 0;
constexpr int RV2_OFF = BB * CC * DD;               // 2560
constexpr int RS_OFF = 2 * BB * CC * DD;            // 5120
constexpr int PAR_BASE = 3 * ACC_SZ;                // 15840
constexpr int PAR_SZ = 3 * BB * CC * DD + BB * CC;  // miu | A | i2s | act = 7840
constexpr int PMIU = 0;
constexpr int PA = BB * CC * DD;
constexpr int PI2S = 2 * BB * CC * DD;
constexpr int PACT = 3 * BB * CC * DD;
constexpr float LOG10x16 = 36.841361487904734f;     // 16*ln(10)
}  // namespace

__global__ void zero_acc(float* ws) {
  int i = blockIdx.x * blockDim.x + threadIdx.x;
  if (i < 3 * ACC_SZ) ws[i] = 0.0f;
}

// Wave-level merge of the 4 row-slots sharing a c within each wave, then
// one atomicAdd per (c,d) from lanes 0..15 of each wave.
template <bool HAS_V2>
__device__ __forceinline__ void reduce_tail(float* __restrict__ acc, int b, int c,
                                            bool active, float* arv, float* arv2,
                                            float ar) {
#pragma unroll
  for (int d = 0; d < DD; ++d) {
    arv[d] += __shfl_down(arv[d], 32);
    arv[d] += __shfl_down(arv[d], 16);
  }
  if (HAS_V2) {
#pragma unroll
    for (int d = 0; d < DD; ++d) {
      arv2[d] += __shfl_down(arv2[d], 32);
      arv2[d] += __shfl_down(arv2[d], 16);
    }
  }
  ar += __shfl_down(ar, 32);
  ar += __shfl_down(ar, 16);
  const int lane = threadIdx.x & 63;
  if (lane < 16 && active) {
    float* rv = acc + RV_OFF + (b * CC + c) * DD;
#pragma unroll
    for (int d = 0; d < DD; ++d) atomicAdd(&rv[d], arv[d]);
    if (HAS_V2) {
      float* rv2 = acc + RV2_OFF + (b * CC + c) * DD;
#pragma unroll
      for (int d = 0; d < DD; ++d) atomicAdd(&rv2[d], arv2[d]);
    }
    atomicAdd(&acc[RS_OFF + b * CC + c], ar);
  }
}

__global__ __launch_bounds__(256) void pass0(const float* __restrict__ votes,
                                             const float* __restrict__ activ,
                                             float* __restrict__ acc) {
  const int b = blockIdx.x / CHUNKS;
  const int chunk = blockIdx.x % CHUNKS;
  const int tid = threadIdx.x;
  const int rslot = tid >> 4;
  const int c = tid & 15;
  const bool active = c < CC;
  float arv[DD], arv2[DD], ar = 0.0f;
#pragma unroll
  for (int d = 0; d < DD; ++d) { arv[d] = 0.0f; arv2[d] = 0.0f; }
  const int n0 = chunk * ROWS_PER_CHUNK;
  for (int rr = rslot; rr < ROWS_PER_CHUNK; rr += 16) {
    const int n = n0 + rr;
    const float a = activ[b * NN + n];
    // r = (a/C) / (sum_c a/C + EPS) = (a/C)/(a + EPS)
    const float r = (a * (1.0f / CC)) / (a + EPSF);
    if (active) {
      const float4* vp =
          (const float4*)(votes + ((size_t)b * NN + n) * (CC * DD) + c * DD);
#pragma unroll
      for (int q = 0; q < 4; ++q) {
        float4 v4 = vp[q];
        float vv[4] = {v4.x, v4.y, v4.z, v4.w};
#pragma unroll
        for (int j = 0; j < 4; ++j) {
          float v = vv[j];
          arv[q * 4 + j] += r * v;
          arv2[q * 4 + j] += r * v * v;
        }
      }
      ar += r;
    }
  }
  reduce_tail<true>(acc, b, c, active, arv, arv2, ar);
}

// IT = 1: accumulate rv, rv2, rsum.  IT = 2: rv, rsum only (miu is the output).
template <int IT>
__global__ __launch_bounds__(256) void pass12(const float* __restrict__ votes,
                                              const float* __restrict__ activ,
                                              const float* __restrict__ par,
                                              float* __restrict__ acc) {
  const int b = blockIdx.x / CHUNKS;
  const int chunk = blockIdx.x % CHUNKS;
  const int tid = threadIdx.x;
  const int rslot = tid >> 4;
  const int c = tid & 15;
  const bool active = c < CC;
  float miu[DD], Ac[DD], i2s[DD], actc = 0.0f;
  if (active) {
    const int pidx = (b * CC + c) * DD;
#pragma unroll
    for (int d = 0; d < DD; ++d) {
      miu[d] = par[PMIU + pidx + d];
      Ac[d] = par[PA + pidx + d];
      i2s[d] = par[PI2S + pidx + d];
    }
    actc = par[PACT + b * CC + c];
  }
  float arv[DD], arv2[DD], ar = 0.0f;
#pragma unroll
  for (int d = 0; d < DD; ++d) { arv[d] = 0.0f; arv2[d] = 0.0f; }
  const int n0 = chunk * ROWS_PER_CHUNK;
  for (int rr = rslot; rr < ROWS_PER_CHUNK; rr += 16) {
    const int n = n0 + rr;
    float v[DD];
    float s = 0.0f, mx = -INFINITY;
    if (active) {
      const float4* vp =
          (const float4*)(votes + ((size_t)b * NN + n) * (CC * DD) + c * DD);
#pragma unroll
      for (int q = 0; q < 4; ++q) {
        float4 v4 = vp[q];
        v[4 * q + 0] = v4.x;
        v[4 * q + 1] = v4.y;
        v[4 * q + 2] = v4.z;
        v[4 * q + 3] = v4.w;
      }
#pragma unroll
      for (int d = 0; d < DD; ++d) {
        float dv = v[d] - miu[d];
        float lp = Ac[d] - dv * dv * i2s[d];
        s += lp;
        mx = fmaxf(mx, lp);
      }
    }
    // max of log_p over (c,d) within the 16-lane c-group
    float M = mx;
    M = fmaxf(M, __shfl_xor(M, 1));
    M = fmaxf(M, __shfl_xor(M, 2));
    M = fmaxf(M, __shfl_xor(M, 4));
    M = fmaxf(M, __shfl_xor(M, 8));
    float p = active ? expf(s - 16.0f * M + LOG10x16) : 0.0f;
    float ap = p * actc;
    float sap = ap;
    sap += __shfl_xor(sap, 1);
    sap += __shfl_xor(sap, 2);
    sap += __shfl_xor(sap, 4);
    sap += __shfl_xor(sap, 8);
    const float a = activ[b * NN + n];
    float r = (ap / (sap + EPSF)) * a;
    // sum_c r = a * sap/(sap+EPS) in closed form
    const float sr = a * (sap / (sap + EPSF));
    r = r / (sr + EPSF);
    if (active) {
      ar += r;
#pragma unroll
      for (int d = 0; d < DD; ++d) {
        arv[d] += r * v[d];
        if (IT == 1) arv2[d] += r * v[d] * v[d];
      }
    }
  }
  reduce_tail<IT == 1>(acc, b, c, active, arv, arv2, ar);
}

// Computes miu (and, unless FINAL, A=-0.5*ln(sigma), 1/(2*sigma), act=softmax(rsum)).
template <bool FINAL>
__global__ void finalize_k(const float* __restrict__ acc, float* __restrict__ par_out,
                           float* __restrict__ out) {
  const int idx = blockIdx.x * blockDim.x + threadIdx.x;
  if (idx < BB * CC * DD) {
    const int bc = idx / DD;
    const float rs = acc[RS_OFF + bc];
    const float den = rs + EPSF;
    const float miu = acc[RV_OFF + idx] / den;
    if (FINAL) {
      out[idx] = miu;
    } else {
      const float rv2 = acc[RV2_OFF + idx];
      const float S = rs / den;
      const float sig = rv2 / den - miu * miu * (2.0f - S) + EPSF;
      par_out[PMIU + idx] = miu;
      par_out[PA + idx] = -0.5f * logf(sig);
      par_out[PI2S + idx] = 0.5f / sig;
    }
  }
  if (!FINAL && blockIdx.x == 0 && threadIdx.x < BB) {
    const int b = threadIdx.x;
    float rsv[CC], e[CC];
    float m = -INFINITY;
    for (int c = 0; c < CC; ++c) {
      rsv[c] = acc[RS_OFF + b * CC + c];
      m = fmaxf(m, rsv[c]);
    }
    float ss = 0.0f;
    for (int c = 0; c < CC; ++c) {
      e[c] = expf(rsv[c] - m);
      ss += e[c];
    }
    for (int c = 0; c < CC; ++c) par_out[PACT + b * CC + c] = e[c] / ss;
  }
}

extern "C" void kernel_launch(void* const* d_in, const int* in_sizes, int n_in,
                              void* d_out, int out_size, void* d_ws, size_t ws_size,
                              hipStream_t stream) {
  const float* votes = (const float*)d_in[0];
  const float* activ = (const float*)d_in[1];
  // d_in[2] (beta_v) and d_in[3] (beta_a) only affect the final act_out,
  // which does not influence the returned miu -> unused.
  float* ws = (float*)d_ws;
  float* out = (float*)d_out;

  zero_acc<<<dim3((3 * ACC_SZ + 255) / 256), dim3(256), 0, stream>>>(ws);

  float* acc0 = ws;
  float* acc1 = ws + ACC_SZ;
  float* acc2 = ws + 2 * ACC_SZ;
  float* par0 = ws + PAR_BASE;
  float* par1 = ws + PAR_BASE + PAR_SZ;

  pass0<<<dim3(BB * CHUNKS), dim3(256), 0, stream>>>(votes, activ, acc0);
  finalize_k<false><<<dim3((BB * CC * DD + 255) / 256), dim3(256), 0, stream>>>(
      acc0, par0, nullptr);
  pass12<1><<<dim3(BB * CHUNKS), dim3(256), 0, stream>>>(votes, activ, par0, acc1);
  finalize_k<false><<<dim3((BB * CC * DD + 255) / 256), dim3(256), 0, stream>>>(
      acc1, par1, nullptr);
  pass12<2><<<dim3(BB * CHUNKS), dim3(256), 0, stream>>>(votes, activ, par1, acc2);
  finalize_k<true><<<dim3((BB * CC * DD + 255) / 256), dim3(256), 0, stream>>>(
      acc2, nullptr, out);
}